// Round 4
// baseline (2228.576 us; speedup 1.0000x reference)
//
#include <hip/hip_runtime.h>
#include <math.h>

#define VOCAB 50257
#define EMB 1024
#define HD 1024
#define TRK 1024
#define LQ 256
#define BND 25
#define NBLK_GRU 64

// ---------------- helpers ----------------
__device__ __forceinline__ float wred(float s){
  #pragma unroll
  for (int m = 32; m >= 1; m >>= 1) s += __shfl_xor(s, m, 64);
  return s;
}

// ---------------- K_pre: gi_base rows + embedding gather ----------------
__global__ __launch_bounds__(256) void k_pre(const float* __restrict__ Wih,
                                             const float* __restrict__ qv,
                                             const float* __restrict__ bih,
                                             const int*   __restrict__ ta,
                                             const float* __restrict__ emb,
                                             float* __restrict__ gib,
                                             float* __restrict__ E){
  int b = blockIdx.x, tid = threadIdx.x;
  if (b < 768){
    int w = tid >> 6, lane = tid & 63;
    int row = b*4 + w;
    const float* a = Wih + (size_t)row*2048;
    float s = 0.f;
    #pragma unroll
    for (int e = 0; e < 4; e++){
      int k = e*256 + lane*4;
      float4 av = *(const float4*)(a + k);
      float4 qr = *(const float4*)(qv + k);
      s += av.x*qr.x + av.y*qr.y + av.z*qr.z + av.w*qr.w;
    }
    s = wred(s);
    if (lane == 0) gib[row] = s + bih[row];
  } else {
    int g = (b - 768)*256 + tid;      // 0..25599
    int t = g >> 10, i = g & 1023;
    int idx = (t == 0) ? 0 : ta[t-1];
    E[g] = emb[(size_t)idx*EMB + i];
  }
}

// ---------------- K_keys: keysT[j][l] partials (k-split x4) ----------------
__global__ __launch_bounds__(256) void k_keys(const float* __restrict__ qw,
                                              const float* __restrict__ Wk,
                                              float* __restrict__ part){
  __shared__ float qt[64*256];
  int jb = blockIdx.x;                // 0..63 -> 16 j's each
  int ks = blockIdx.y;                // 0..3  -> k-chunk of 256
  int tid = threadIdx.x;
  int l = tid;
  float acc[16];
  #pragma unroll
  for (int j = 0; j < 16; j++) acc[j] = 0.f;

  for (int kt = 0; kt < 4; kt++){
    int kb = ks*256 + kt*64;
    __syncthreads();
    #pragma unroll
    for (int p = 0; p < 16; p++){
      int fidx = (p*256 + tid)*4;
      int kk = fidx & 63, ll = fidx >> 6;
      float4 v = *(const float4*)(qw + (size_t)ll*1024 + kb + kk);
      qt[(kk+0)*256 + (ll ^ ((kk+0)&31))] = v.x;
      qt[(kk+1)*256 + (ll ^ ((kk+1)&31))] = v.y;
      qt[(kk+2)*256 + (ll ^ ((kk+2)&31))] = v.z;
      qt[(kk+3)*256 + (ll ^ ((kk+3)&31))] = v.w;
    }
    __syncthreads();
    #pragma unroll
    for (int s = 0; s < 4; s++){
      float qr[16];
      #pragma unroll
      for (int q = 0; q < 16; q++){
        int k = s*16 + q;
        qr[q] = qt[k*256 + (l ^ (k&31))];
      }
      #pragma unroll
      for (int j = 0; j < 16; j++){
        const float* wr = Wk + (size_t)(jb*16 + j)*1024 + kb + s*16;
        #pragma unroll
        for (int q4 = 0; q4 < 4; q4++){
          float4 wv = *(const float4*)(wr + q4*4);
          acc[j] += qr[q4*4+0]*wv.x + qr[q4*4+1]*wv.y
                  + qr[q4*4+2]*wv.z + qr[q4*4+3]*wv.w;
        }
      }
    }
  }
  #pragma unroll
  for (int j = 0; j < 16; j++)
    part[((size_t)ks*1024 + jb*16 + j)*256 + l] = acc[j];
}

// ---------------- K_gemm_s2: skinny GEMM, wave-per-row, chunked B staging ----------------
// C[t*R + row] = act( A[row][0:K] . B[t][0:K] + bias[row] );  NCH*K*4 = 64KB LDS
template<int K, int NCH>
__global__ __launch_bounds__(256) void k_gemm_s2(const float* __restrict__ A, int lda,
                                                 const float* __restrict__ B, int ldb,
                                                 const float* __restrict__ bias,
                                                 float* __restrict__ C,
                                                 int R, int N, int act){
  __shared__ float Bl[NCH*K];
  constexpr int KD4 = K/4;
  int tid = threadIdx.x, w = tid >> 6, lane = tid & 63;
  int row = blockIdx.x*4 + w;
  const float* a = A + (size_t)row*lda;
  float4 ar[K/256];
  #pragma unroll
  for (int e = 0; e < K/256; e++)
    ar[e] = *(const float4*)(a + e*256 + lane*4);
  float bs = bias[row];
  for (int c0 = 0; c0 < N; c0 += NCH){
    int nt = min(NCH, N - c0);
    __syncthreads();
    int total = nt*KD4;
    for (int i = tid; i < total; i += 256){
      int j = i/KD4, kk = i - j*KD4;
      *(float4*)&Bl[j*K + kk*4] = *(const float4*)(B + (size_t)(c0+j)*ldb + kk*4);
    }
    __syncthreads();
    for (int j = 0; j < nt; j++){
      float s = 0.f;
      #pragma unroll
      for (int e = 0; e < K/256; e++){
        float4 bv = *(const float4*)&Bl[j*K + e*256 + lane*4];
        s += ar[e].x*bv.x + ar[e].y*bv.y + ar[e].z*bv.z + ar[e].w*bv.w;
      }
      s = wred(s);
      if (lane == 0){
        float v = s + bs;
        if (act) v = tanhf(v);
        C[(size_t)(c0+j)*R + row] = v;
      }
    }
  }
}

// ---------------- K_gru3: 25 GRU steps, 64 blocks x 1024 thr, flag-array barrier ----------------
// No RMW contention: block b release-stores flags[b*32]=t+1 (own 128B line);
// wave 0 of each block polls all 64 flags (one per lane) until __all(>= t+1).
__global__ __launch_bounds__(1024) void k_gru3(const float* __restrict__ Whh,
                                               const float* __restrict__ bhh,
                                               const float* __restrict__ gi,
                                               const float* __restrict__ dv,
                                               float* __restrict__ HC,
                                               int* __restrict__ flags){
  __shared__ float sres[48];
  int tid = threadIdx.x, w = tid >> 6, lane = tid & 63;
  int iBase = blockIdx.x*16;

  for (int t = 0; t < BND; t++){
    const float* hp = (t == 0) ? dv : (HC + (size_t)(t-1)*2048);
    float hv[16];
    #pragma unroll
    for (int c = 0; c < 4; c++){
      float4 v = *(const float4*)(hp + c*256 + lane*4);
      hv[c*4]=v.x; hv[c*4+1]=v.y; hv[c*4+2]=v.z; hv[c*4+3]=v.w;
    }
    #pragma unroll
    for (int j = 0; j < 3; j++){
      int d = w*3 + j;
      int g = d >> 4, s = d & 15;
      const float* wr = Whh + (size_t)(g*1024 + iBase + s)*1024;
      float a = 0.f;
      #pragma unroll
      for (int c = 0; c < 4; c++){
        float4 v = *(const float4*)(wr + c*256 + lane*4);
        a += v.x*hv[c*4] + v.y*hv[c*4+1] + v.z*hv[c*4+2] + v.w*hv[c*4+3];
      }
      a = wred(a);
      if (lane == 0) sres[d] = a;
    }
    __syncthreads();
    if (tid < 16){
      int i = iBase + tid;
      const float* gg = gi + (size_t)t*3072;
      float ghr = sres[tid]    + bhh[i];
      float ghz = sres[16+tid] + bhh[1024+i];
      float ghn = sres[32+tid] + bhh[2048+i];
      float rr = 1.f/(1.f + expf(-(gg[i]      + ghr)));
      float zz = 1.f/(1.f + expf(-(gg[1024+i] + ghz)));
      float nn = tanhf(gg[2048+i] + rr*ghn);
      HC[(size_t)t*2048 + i] = (1.f - zz)*nn + zz*hp[i];
    }
    if (t == BND-1) break;
    __threadfence();
    __syncthreads();
    if (tid == 0)
      __hip_atomic_store(&flags[blockIdx.x*32], t+1, __ATOMIC_RELEASE, __HIP_MEMORY_SCOPE_AGENT);
    if (w == 0){
      for (;;){
        int v = __hip_atomic_load(&flags[lane*32], __ATOMIC_ACQUIRE, __HIP_MEMORY_SCOPE_AGENT);
        if (__all(v >= t+1)) break;
        __builtin_amdgcn_s_sleep(1);
      }
    }
    __syncthreads();
  }
}

// ---------------- K_attn1: e partials over j-chunks (folds keys reduction) ----------------
__global__ __launch_bounds__(256) void k_attn1(const float* __restrict__ part,
                                               const float* __restrict__ bk,
                                               const float* __restrict__ Qt,
                                               const float* __restrict__ av,
                                               float* __restrict__ epart){
  int t = blockIdx.x, jc = blockIdx.y;
  int l = threadIdx.x;
  const float* q = Qt + (size_t)t*1024;
  float acc = 0.f;
  for (int j = jc*128; j < jc*128 + 128; j++){
    float kv = part[(size_t)j*256 + l]
             + part[(size_t)(1024+j)*256 + l]
             + part[(size_t)(2048+j)*256 + l]
             + part[(size_t)(3072+j)*256 + l]
             + bk[j];
    acc += tanhf(kv + q[j]) * av[j];
  }
  epart[((size_t)t*8 + jc)*256 + l] = acc;
}

// ---------------- K_attn2: softmax over l + ctx = w @ qw ----------------
__global__ __launch_bounds__(256) void k_attn2(const float* __restrict__ epart,
                                               const float* __restrict__ qw,
                                               float* __restrict__ HC){
  __shared__ float red[256];
  __shared__ float sw[256];
  int t = blockIdx.x, tid = threadIdx.x;
  float e = 0.f;
  for (int jc = 0; jc < 8; jc++) e += epart[((size_t)t*8 + jc)*256 + tid];
  red[tid] = e; __syncthreads();
  for (int s = 128; s > 0; s >>= 1){
    if (tid < s) red[tid] = fmaxf(red[tid], red[tid+s]);
    __syncthreads();
  }
  float m = red[0]; __syncthreads();
  float wv = expf(e - m);
  red[tid] = wv; __syncthreads();
  for (int s = 128; s > 0; s >>= 1){
    if (tid < s) red[tid] += red[tid+s];
    __syncthreads();
  }
  float inv = 1.f/red[0];
  sw[tid] = wv*inv; __syncthreads();
  float4 c = make_float4(0.f,0.f,0.f,0.f);
  const float* qp = qw + tid*4;
  for (int ll = 0; ll < 256; ll++){
    float wl = sw[ll];
    float4 v = *(const float4*)(qp + (size_t)ll*1024);
    c.x += wl*v.x; c.y += wl*v.y; c.z += wl*v.z; c.w += wl*v.w;
  }
  *(float4*)(HC + (size_t)t*2048 + 1024 + tid*4) = c;
}

// ---------------- K_gemm_big4: 50257x1024 @ 1024x25, reg-streamed A ----------------
// 786 blocks x 512 thr (8 waves); lane=row (64 rows/block); wave owns k-eighth (128).
// A: two 16-float4 reg batches (256B in flight/lane-wave), FMA direct (no LDS round-trip).
// B: wave-uniform loads (L2-resident). 2 blocks/CU -> 16 waves/CU -> ~4KB in flight/CU.
__global__ __launch_bounds__(512, 4) void k_gemm_big4(const float* __restrict__ A,
                                                      const float* __restrict__ B,
                                                      const float* __restrict__ bias,
                                                      float* __restrict__ C){
  __shared__ float sred[7*25*64];     // 44.8KB: waves 1..7 partial dump
  int tid = threadIdx.x, lane = tid & 63, wu = tid >> 6;   // wu 0..7
  int rowBase = blockIdx.x*64;
  int row = rowBase + lane;
  int rowc = (row < VOCAB) ? row : (VOCAB-1);
  const float* ap = A + (size_t)rowc*1024 + wu*128;
  const float* bp = B + wu*128;

  float acc[25];
  #pragma unroll
  for (int t = 0; t < 25; t++) acc[t] = 0.f;

  #pragma unroll 1
  for (int batch = 0; batch < 2; batch++){
    float4 a[16];
    #pragma unroll
    for (int j = 0; j < 16; j++)
      a[j] = *(const float4*)(ap + batch*64 + j*4);
    #pragma unroll
    for (int j = 0; j < 16; j++){
      #pragma unroll
      for (int t = 0; t < 25; t++){
        float4 b = *(const float4*)(bp + (size_t)t*1024 + batch*64 + j*4);
        acc[t] += a[j].x*b.x + a[j].y*b.y + a[j].z*b.z + a[j].w*b.w;
      }
    }
  }
  __syncthreads();
  if (wu > 0){
    #pragma unroll
    for (int t = 0; t < 25; t++)
      sred[((wu-1)*25 + t)*64 + lane] = acc[t];
  }
  __syncthreads();
  if (wu == 0 && row < VOCAB){
    float bs = bias[row];
    #pragma unroll
    for (int t = 0; t < 25; t++){
      float s = acc[t] + bs;
      #pragma unroll
      for (int q = 0; q < 7; q++)
        s += sred[(q*25 + t)*64 + lane];
      C[(size_t)t*VOCAB + row] = s;
    }
  }
}

// ---------------- K_logsm: per-row log_softmax (in place) + argmax ----------------
__global__ __launch_bounds__(256) void k_logsm(float* __restrict__ out){
  __shared__ float rv[256];
  __shared__ int   ri[256];
  int t = blockIdx.x, tid = threadIdx.x;
  float* p = out + 25 + (size_t)t*VOCAB;
  float m = -3.4e38f; int mi = 0;
  for (int k = tid; k < VOCAB; k += 256){
    float v = p[k];
    if (v > m){ m = v; mi = k; }
  }
  rv[tid] = m; ri[tid] = mi; __syncthreads();
  for (int s = 128; s > 0; s >>= 1){
    if (tid < s){
      if (rv[tid+s] > rv[tid] || (rv[tid+s] == rv[tid] && ri[tid+s] < ri[tid])){
        rv[tid] = rv[tid+s]; ri[tid] = ri[tid+s];
      }
    }
    __syncthreads();
  }
  float M = rv[0]; int aidx = ri[0];
  __syncthreads();
  float sum = 0.f;
  for (int k = tid; k < VOCAB; k += 256) sum += expf(p[k] - M);
  rv[tid] = sum; __syncthreads();
  for (int s = 128; s > 0; s >>= 1){
    if (tid < s) rv[tid] += rv[tid+s];
    __syncthreads();
  }
  float Lg = logf(rv[0]) + M;
  for (int k = tid; k < VOCAB; k += 256) p[k] = p[k] - Lg;
  if (tid == 0) out[t] = (float)aidx;
}

// ---------------- launch ----------------
extern "C" void kernel_launch(void* const* d_in, const int* in_sizes, int n_in,
                              void* d_out, int out_size, void* d_ws, size_t ws_size,
                              hipStream_t stream){
  const float* qw  = (const float*)d_in[0];
  const float* qv  = (const float*)d_in[1];
  const float* dv  = (const float*)d_in[2];
  const int*   ta  = (const int*)d_in[3];
  const float* emb = (const float*)d_in[4];
  const float* Wih = (const float*)d_in[5];
  const float* Whh = (const float*)d_in[6];
  const float* bih = (const float*)d_in[7];
  const float* bhh = (const float*)d_in[8];
  const float* Wq  = (const float*)d_in[9];
  const float* bq  = (const float*)d_in[10];
  const float* Wk  = (const float*)d_in[11];
  const float* bk  = (const float*)d_in[12];
  const float* av  = (const float*)d_in[13];
  const float* cW  = (const float*)d_in[14];
  const float* cb  = (const float*)d_in[15];
  const float* oW  = (const float*)d_in[16];
  const float* ob  = (const float*)d_in[17];
  float* out = (float*)d_out;
  float* ws  = (float*)d_ws;

  float* part  = ws;                 // 1048576 (4 x 1024 x 256)
  float* E     = ws + 1048576;       // 25600
  float* gib   = ws + 1074176;       // 3072
  float* gi    = ws + 1077248;       // 76800
  float* HC    = ws + 1154048;       // 51200 (25 x [h(1024) | ctx(1024)])
  float* Qt    = ws + 1205248;       // 25600
  float* VEC   = ws + 1230848;       // 25600
  float* ep    = ws + 1256448;       // 51200
  int*   flags = (int*)(ws + 1310720); // 2048 ints (64 flags x 128B stride)

  hipMemsetAsync(flags, 0, 2048*4, stream);
  k_pre<<<868, 256, 0, stream>>>(Wih, qv, bih, ta, emb, gib, E);
  k_keys<<<dim3(64,4), 256, 0, stream>>>(qw, Wk, part);
  k_gemm_s2<1024,16><<<768, 256, 0, stream>>>(Wih + 1024, 2048, E, 1024, gib, gi, 3072, 25, 0);
  k_gru3<<<NBLK_GRU, 1024, 0, stream>>>(Whh, bhh, gi, dv, HC, flags);
  k_gemm_s2<1024,16><<<256, 256, 0, stream>>>(Wq, 1024, HC, 2048, bq, Qt, 1024, 25, 0);
  k_attn1<<<dim3(25,8), 256, 0, stream>>>(part, bk, Qt, av, ep);
  k_attn2<<<25, 256, 0, stream>>>(ep, qw, HC);
  k_gemm_s2<2048,8><<<256, 256, 0, stream>>>(cW, 2048, HC, 2048, cb, VEC, 1024, 25, 1);
  k_gemm_big4<<<786, 512, 0, stream>>>(oW, VEC, ob, out + 25);
  k_logsm<<<25, 256, 0, stream>>>(out);
}

// Round 5
// 620.986 us; speedup vs baseline: 3.5888x; 3.5888x over previous
//
#include <hip/hip_runtime.h>
#include <math.h>

#define VOCAB 50257
#define EMB 1024
#define HD 1024
#define TRK 1024
#define LQ 256
#define BND 25

// ---------------- helpers ----------------
__device__ __forceinline__ float wred(float s){
  #pragma unroll
  for (int m = 32; m >= 1; m >>= 1) s += __shfl_xor(s, m, 64);
  return s;
}

// ---------------- K_pre: gi_base rows + embedding gather ----------------
__global__ __launch_bounds__(256) void k_pre(const float* __restrict__ Wih,
                                             const float* __restrict__ qv,
                                             const float* __restrict__ bih,
                                             const int*   __restrict__ ta,
                                             const float* __restrict__ emb,
                                             float* __restrict__ gib,
                                             float* __restrict__ E){
  int b = blockIdx.x, tid = threadIdx.x;
  if (b < 768){
    int w = tid >> 6, lane = tid & 63;
    int row = b*4 + w;
    const float* a = Wih + (size_t)row*2048;
    float s = 0.f;
    #pragma unroll
    for (int e = 0; e < 4; e++){
      int k = e*256 + lane*4;
      float4 av = *(const float4*)(a + k);
      float4 qr = *(const float4*)(qv + k);
      s += av.x*qr.x + av.y*qr.y + av.z*qr.z + av.w*qr.w;
    }
    s = wred(s);
    if (lane == 0) gib[row] = s + bih[row];
  } else {
    int g = (b - 768)*256 + tid;      // 0..25599
    int t = g >> 10, i = g & 1023;
    int idx = (t == 0) ? 0 : ta[t-1];
    E[g] = emb[(size_t)idx*EMB + i];
  }
}

// ---------------- K_keys: keysT[j][l] partials (k-split x4) ----------------
__global__ __launch_bounds__(256) void k_keys(const float* __restrict__ qw,
                                              const float* __restrict__ Wk,
                                              float* __restrict__ part){
  __shared__ float qt[64*256];
  int jb = blockIdx.x;                // 0..63 -> 16 j's each
  int ks = blockIdx.y;                // 0..3  -> k-chunk of 256
  int tid = threadIdx.x;
  int l = tid;
  float acc[16];
  #pragma unroll
  for (int j = 0; j < 16; j++) acc[j] = 0.f;

  for (int kt = 0; kt < 4; kt++){
    int kb = ks*256 + kt*64;
    __syncthreads();
    #pragma unroll
    for (int p = 0; p < 16; p++){
      int fidx = (p*256 + tid)*4;
      int kk = fidx & 63, ll = fidx >> 6;
      float4 v = *(const float4*)(qw + (size_t)ll*1024 + kb + kk);
      qt[(kk+0)*256 + (ll ^ ((kk+0)&31))] = v.x;
      qt[(kk+1)*256 + (ll ^ ((kk+1)&31))] = v.y;
      qt[(kk+2)*256 + (ll ^ ((kk+2)&31))] = v.z;
      qt[(kk+3)*256 + (ll ^ ((kk+3)&31))] = v.w;
    }
    __syncthreads();
    #pragma unroll
    for (int s = 0; s < 4; s++){
      float qr[16];
      #pragma unroll
      for (int q = 0; q < 16; q++){
        int k = s*16 + q;
        qr[q] = qt[k*256 + (l ^ (k&31))];
      }
      #pragma unroll
      for (int j = 0; j < 16; j++){
        const float* wr = Wk + (size_t)(jb*16 + j)*1024 + kb + s*16;
        #pragma unroll
        for (int q4 = 0; q4 < 4; q4++){
          float4 wv = *(const float4*)(wr + q4*4);
          acc[j] += qr[q4*4+0]*wv.x + qr[q4*4+1]*wv.y
                  + qr[q4*4+2]*wv.z + qr[q4*4+3]*wv.w;
        }
      }
    }
  }
  #pragma unroll
  for (int j = 0; j < 16; j++)
    part[((size_t)ks*1024 + jb*16 + j)*256 + l] = acc[j];
}

// ---------------- K_keys_red: keysT = sum of 4 partials + bk[j] ----------------
__global__ __launch_bounds__(256) void k_keys_red(const float* __restrict__ part,
                                                  const float* __restrict__ bk,
                                                  float* __restrict__ keysT){
  int g = blockIdx.x*256 + threadIdx.x;   // 65536 threads * 4 floats
  int base = g*4;
  float4 s0 = *(const float4*)(part + base);
  float4 s1 = *(const float4*)(part + 262144 + base);
  float4 s2 = *(const float4*)(part + 524288 + base);
  float4 s3 = *(const float4*)(part + 786432 + base);
  float b = bk[base >> 8];
  float4 r;
  r.x = s0.x + s1.x + s2.x + s3.x + b;
  r.y = s0.y + s1.y + s2.y + s3.y + b;
  r.z = s0.z + s1.z + s2.z + s3.z + b;
  r.w = s0.w + s1.w + s2.w + s3.w + b;
  *(float4*)(keysT + base) = r;
}

// ---------------- K_gemm_s2: skinny GEMM, wave-per-row, chunked B staging ----------------
template<int K, int NCH>
__global__ __launch_bounds__(256) void k_gemm_s2(const float* __restrict__ A, int lda,
                                                 const float* __restrict__ B, int ldb,
                                                 const float* __restrict__ bias,
                                                 float* __restrict__ C,
                                                 int R, int N, int act){
  __shared__ float Bl[NCH*K];
  constexpr int KD4 = K/4;
  int tid = threadIdx.x, w = tid >> 6, lane = tid & 63;
  int row = blockIdx.x*4 + w;
  const float* a = A + (size_t)row*lda;
  float4 ar[K/256];
  #pragma unroll
  for (int e = 0; e < K/256; e++)
    ar[e] = *(const float4*)(a + e*256 + lane*4);
  float bs = bias[row];
  for (int c0 = 0; c0 < N; c0 += NCH){
    int nt = min(NCH, N - c0);
    __syncthreads();
    int total = nt*KD4;
    for (int i = tid; i < total; i += 256){
      int j = i/KD4, kk = i - j*KD4;
      *(float4*)&Bl[j*K + kk*4] = *(const float4*)(B + (size_t)(c0+j)*ldb + kk*4);
    }
    __syncthreads();
    for (int j = 0; j < nt; j++){
      float s = 0.f;
      #pragma unroll
      for (int e = 0; e < K/256; e++){
        float4 bv = *(const float4*)&Bl[j*K + e*256 + lane*4];
        s += ar[e].x*bv.x + ar[e].y*bv.y + ar[e].z*bv.z + ar[e].w*bv.w;
      }
      s = wred(s);
      if (lane == 0){
        float v = s + bs;
        if (act) v = tanhf(v);
        C[(size_t)(c0+j)*R + row] = v;
      }
    }
  }
}

// ---------------- K_gru4: 25 GRU steps; Whh in LDS; L3-atomic h exchange ----------------
// 256 blocks x 256 thr. Block b owns h[4b..4b+4): 12 gate rows in LDS (48KB).
// Exchange lines: hx[b*8..]: 4 data floats + flag int at +4. All cross-block
// traffic via relaxed AGENT atomics (sc1 -> coherent point), no fences.
__global__ __launch_bounds__(256, 2) void k_gru4(const float* __restrict__ Whh,
                                                 const float* __restrict__ bhh,
                                                 const float* __restrict__ gi,
                                                 const float* __restrict__ dv,
                                                 float* __restrict__ HC,
                                                 float* __restrict__ hx){
  __shared__ float Wl[12][1024];
  __shared__ float hbuf[1024];
  __shared__ float sres[12];
  int tid = threadIdx.x, w = tid >> 6, lane = tid & 63;
  int b = blockIdx.x;
  // preload 12 gate rows: LDS row r=(g*4+s) <- Whh[g*1024 + b*4 + s]
  for (int i = tid; i < 3072; i += 256){
    int r = i >> 8, c = (i & 255)*4;
    int g = r >> 2, s = r & 3;
    *(float4*)&Wl[r][c] = *(const float4*)(Whh + (size_t)(g*1024 + b*4 + s)*1024 + c);
  }
  *(float4*)&hbuf[tid*4] = *(const float4*)(dv + tid*4);
  __syncthreads();

  for (int t = 0; t < BND; t++){
    float g0=0,g1=0,g2=0,bb0=0,bb1=0,bb2=0,hpown=0;
    if (tid < 4){
      int i = b*4 + tid;
      const float* gg = gi + (size_t)t*3072;
      g0 = gg[i]; g1 = gg[1024+i]; g2 = gg[2048+i];
      bb0 = bhh[i]; bb1 = bhh[1024+i]; bb2 = bhh[2048+i];
      hpown = hbuf[i];
    }
    // dots: wave w -> LDS rows 3w..3w+2; lane owns k = e*256 + lane*4 (+0..3)
    float hv[16];
    #pragma unroll
    for (int e = 0; e < 4; e++){
      float4 v = *(const float4*)&hbuf[e*256 + lane*4];
      hv[e*4]=v.x; hv[e*4+1]=v.y; hv[e*4+2]=v.z; hv[e*4+3]=v.w;
    }
    #pragma unroll
    for (int j = 0; j < 3; j++){
      int r = w*3 + j;
      float a = 0.f;
      #pragma unroll
      for (int e = 0; e < 4; e++){
        float4 v = *(const float4*)&Wl[r][e*256 + lane*4];
        a += v.x*hv[e*4] + v.y*hv[e*4+1] + v.z*hv[e*4+2] + v.w*hv[e*4+3];
      }
      a = wred(a);
      if (lane == 0) sres[r] = a;
    }
    __syncthreads();
    if (tid < 4){
      int i = b*4 + tid;
      float ghr = sres[tid]   + bb0;
      float ghz = sres[4+tid] + bb1;
      float ghn = sres[8+tid] + bb2;
      float rr = 1.f/(1.f + expf(-(g0 + ghr)));
      float zz = 1.f/(1.f + expf(-(g1 + ghz)));
      float nn = tanhf(g2 + rr*ghn);
      float hnew = (1.f - zz)*nn + zz*hpown;
      HC[(size_t)t*2048 + i] = hnew;
      if (t < BND-1){
        __hip_atomic_store(hx + b*8 + tid, hnew, __ATOMIC_RELAXED, __HIP_MEMORY_SCOPE_AGENT);
        asm volatile("s_waitcnt vmcnt(0)" ::: "memory");
      }
    }
    if (t == BND-1) break;
    __syncthreads();
    if (tid == 0)
      __hip_atomic_store((int*)(hx + b*8 + 4), t+1, __ATOMIC_RELAXED, __HIP_MEMORY_SCOPE_AGENT);
    if (w == 0){
      // lane handles lines lane, 64+lane, 128+lane, 192+lane
      for (;;){
        int f0 = __hip_atomic_load((const int*)(hx + (lane      )*8 + 4), __ATOMIC_RELAXED, __HIP_MEMORY_SCOPE_AGENT);
        int f1 = __hip_atomic_load((const int*)(hx + (64  + lane)*8 + 4), __ATOMIC_RELAXED, __HIP_MEMORY_SCOPE_AGENT);
        int f2 = __hip_atomic_load((const int*)(hx + (128 + lane)*8 + 4), __ATOMIC_RELAXED, __HIP_MEMORY_SCOPE_AGENT);
        int f3 = __hip_atomic_load((const int*)(hx + (192 + lane)*8 + 4), __ATOMIC_RELAXED, __HIP_MEMORY_SCOPE_AGENT);
        if (min(min(f0,f1),min(f2,f3)) >= t+1) break;
        __builtin_amdgcn_s_sleep(2);
      }
      #pragma unroll
      for (int q = 0; q < 4; q++){
        float d0 = __hip_atomic_load(hx + (q*64 + lane)*8 + 0, __ATOMIC_RELAXED, __HIP_MEMORY_SCOPE_AGENT);
        float d1 = __hip_atomic_load(hx + (q*64 + lane)*8 + 1, __ATOMIC_RELAXED, __HIP_MEMORY_SCOPE_AGENT);
        float d2 = __hip_atomic_load(hx + (q*64 + lane)*8 + 2, __ATOMIC_RELAXED, __HIP_MEMORY_SCOPE_AGENT);
        float d3 = __hip_atomic_load(hx + (q*64 + lane)*8 + 3, __ATOMIC_RELAXED, __HIP_MEMORY_SCOPE_AGENT);
        hbuf[q*256 + lane*4 + 0] = d0;
        hbuf[q*256 + lane*4 + 1] = d1;
        hbuf[q*256 + lane*4 + 2] = d2;
        hbuf[q*256 + lane*4 + 3] = d3;
      }
    }
    __syncthreads();
  }
}

// ---------------- K_attn1: e partials over j-chunks ----------------
__global__ __launch_bounds__(256) void k_attn1(const float* __restrict__ keysT,
                                               const float* __restrict__ Qt,
                                               const float* __restrict__ av,
                                               float* __restrict__ epart){
  int t = blockIdx.x, jc = blockIdx.y;
  int l = threadIdx.x;
  const float* q = Qt + (size_t)t*1024;
  float acc = 0.f;
  for (int j = jc*128; j < jc*128 + 128; j++){
    float kv = keysT[(size_t)j*256 + l];
    acc += tanhf(kv + q[j]) * av[j];
  }
  epart[((size_t)t*8 + jc)*256 + l] = acc;
}

// ---------------- K_attn2: softmax over l + ctx = w @ qw ----------------
__global__ __launch_bounds__(256) void k_attn2(const float* __restrict__ epart,
                                               const float* __restrict__ qw,
                                               float* __restrict__ HC){
  __shared__ float red[256];
  __shared__ float sw[256];
  int t = blockIdx.x, tid = threadIdx.x;
  float e = 0.f;
  for (int jc = 0; jc < 8; jc++) e += epart[((size_t)t*8 + jc)*256 + tid];
  red[tid] = e; __syncthreads();
  for (int s = 128; s > 0; s >>= 1){
    if (tid < s) red[tid] = fmaxf(red[tid], red[tid+s]);
    __syncthreads();
  }
  float m = red[0]; __syncthreads();
  float wv = expf(e - m);
  red[tid] = wv; __syncthreads();
  for (int s = 128; s > 0; s >>= 1){
    if (tid < s) red[tid] += red[tid+s];
    __syncthreads();
  }
  float inv = 1.f/red[0];
  sw[tid] = wv*inv; __syncthreads();
  float4 c = make_float4(0.f,0.f,0.f,0.f);
  const float* qp = qw + tid*4;
  for (int ll = 0; ll < 256; ll++){
    float wl = sw[ll];
    float4 v = *(const float4*)(qp + (size_t)ll*1024);
    c.x += wl*v.x; c.y += wl*v.y; c.z += wl*v.z; c.w += wl*v.w;
  }
  *(float4*)(HC + (size_t)t*2048 + 1024 + tid*4) = c;
}

// ---------------- K_gemm_big5: 50257x1024 @ 1024x25, thread-per-row ----------------
// 197 blocks x 256 thr; thread owns one row; acc[25]+pipeline ~70 VGPR,
// bounds(256,1) -> VGPR budget 512 -> cannot spill. B wave-uniform from L2.
__global__ __launch_bounds__(256, 1) void k_gemm_big5(const float* __restrict__ A,
                                                      const float* __restrict__ B,
                                                      const float* __restrict__ bias,
                                                      float* __restrict__ C){
  int tid = threadIdx.x;
  int row = blockIdx.x*256 + tid;
  int rowc = (row < VOCAB) ? row : (VOCAB-1);
  const float* ap = A + (size_t)rowc*1024;
  float acc[25];
  #pragma unroll
  for (int t = 0; t < 25; t++) acc[t] = 0.f;
  float4 a0 = *(const float4*)(ap + 0);
  float4 a1 = *(const float4*)(ap + 4);
  float4 a2 = *(const float4*)(ap + 8);
  float4 a3 = *(const float4*)(ap + 12);
  for (int kb = 0; kb < 1024; kb += 16){
    float4 n0, n1, n2, n3;
    if (kb + 16 < 1024){
      n0 = *(const float4*)(ap + kb + 16);
      n1 = *(const float4*)(ap + kb + 20);
      n2 = *(const float4*)(ap + kb + 24);
      n3 = *(const float4*)(ap + kb + 28);
    }
    #pragma unroll
    for (int t = 0; t < 25; t++){
      const float* bt = B + t*1024 + kb;
      float4 b0 = *(const float4*)(bt + 0);
      float4 b1 = *(const float4*)(bt + 4);
      float4 b2 = *(const float4*)(bt + 8);
      float4 b3 = *(const float4*)(bt + 12);
      acc[t] += a0.x*b0.x + a0.y*b0.y + a0.z*b0.z + a0.w*b0.w
              + a1.x*b1.x + a1.y*b1.y + a1.z*b1.z + a1.w*b1.w
              + a2.x*b2.x + a2.y*b2.y + a2.z*b2.z + a2.w*b2.w
              + a3.x*b3.x + a3.y*b3.y + a3.z*b3.z + a3.w*b3.w;
    }
    a0 = n0; a1 = n1; a2 = n2; a3 = n3;
  }
  if (row < VOCAB){
    float bs = bias[row];
    #pragma unroll
    for (int t = 0; t < 25; t++) C[(size_t)t*VOCAB + row] = acc[t] + bs;
  }
}

// ---------------- K_lstat: per (t, chunk) online max/argmax/sumexp ----------------
__global__ __launch_bounds__(256) void k_lstat(const float* __restrict__ C,
                                               float* __restrict__ pm,
                                               float* __restrict__ ps,
                                               int*   __restrict__ pa){
  __shared__ float sm[256], ss[256];
  __shared__ int   sa[256];
  int t = blockIdx.x, c = blockIdx.y, tid = threadIdx.x;
  int r0 = c*6283, r1 = min(r0 + 6283, VOCAB);
  const float* p = C + (size_t)t*VOCAB;
  float m = -3.4e38f, s = 0.f; int arg = r0;
  for (int r = r0 + tid; r < r1; r += 256){
    float x = p[r];
    if (x > m){ s = s*expf(m - x) + 1.f; m = x; arg = r; }
    else       s += expf(x - m);
  }
  sm[tid] = m; ss[tid] = s; sa[tid] = arg; __syncthreads();
  for (int st = 128; st > 0; st >>= 1){
    if (tid < st){
      float m1 = sm[tid], s1 = ss[tid]; int a1 = sa[tid];
      float m2 = sm[tid+st], s2 = ss[tid+st]; int a2 = sa[tid+st];
      if (m2 > m1){ sm[tid] = m2; ss[tid] = s2 + s1*expf(m1 - m2); sa[tid] = a2; }
      else if (m2 == m1){ ss[tid] = s1 + s2; sa[tid] = min(a1, a2); }
      else { ss[tid] = s1 + s2*expf(m2 - m1); }
    }
    __syncthreads();
  }
  if (tid == 0){ pm[t*8 + c] = sm[0]; ps[t*8 + c] = ss[0]; pa[t*8 + c] = sa[0]; }
}

// ---------------- K_lfin: combine 8 chunks -> Lg[t], out[t]=argmax ----------------
__global__ void k_lfin(const float* __restrict__ pm, const float* __restrict__ ps,
                       const int* __restrict__ pa, float* __restrict__ Lg,
                       float* __restrict__ out){
  int t = threadIdx.x;
  if (t < 25){
    float M = pm[t*8], S = ps[t*8]; int A = pa[t*8];
    for (int c = 1; c < 8; c++){
      float m2 = pm[t*8+c], s2 = ps[t*8+c]; int a2 = pa[t*8+c];
      if (m2 > M){ S = s2 + S*expf(M - m2); M = m2; A = a2; }
      else if (m2 == M){ S += s2; A = min(A, a2); }
      else S += s2*expf(m2 - M);
    }
    Lg[t] = logf(S) + M;
    out[t] = (float)A;
  }
}

// ---------------- K_lsub: p -= Lg[t] ----------------
__global__ __launch_bounds__(256) void k_lsub(float* __restrict__ C,
                                              const float* __restrict__ Lg){
  int t = blockIdx.y;
  int r = blockIdx.x*256 + threadIdx.x;
  if (r < VOCAB) C[(size_t)t*VOCAB + r] -= Lg[t];
}

// ---------------- launch ----------------
extern "C" void kernel_launch(void* const* d_in, const int* in_sizes, int n_in,
                              void* d_out, int out_size, void* d_ws, size_t ws_size,
                              hipStream_t stream){
  const float* qw  = (const float*)d_in[0];
  const float* qv  = (const float*)d_in[1];
  const float* dv  = (const float*)d_in[2];
  const int*   ta  = (const int*)d_in[3];
  const float* emb = (const float*)d_in[4];
  const float* Wih = (const float*)d_in[5];
  const float* Whh = (const float*)d_in[6];
  const float* bih = (const float*)d_in[7];
  const float* bhh = (const float*)d_in[8];
  const float* Wq  = (const float*)d_in[9];
  const float* bq  = (const float*)d_in[10];
  const float* Wk  = (const float*)d_in[11];
  const float* bk  = (const float*)d_in[12];
  const float* av  = (const float*)d_in[13];
  const float* cW  = (const float*)d_in[14];
  const float* cb  = (const float*)d_in[15];
  const float* oW  = (const float*)d_in[16];
  const float* ob  = (const float*)d_in[17];
  float* out = (float*)d_out;
  float* ws  = (float*)d_ws;

  float* part  = ws;                 // 1048576 (dead after keys_red)
  float* pm    = ws;                 // 200   (aliases part; used post-big5)
  float* ps    = ws + 256;           // 200
  int*   pa    = (int*)(ws + 512);   // 200
  float* Lg    = ws + 768;           // 25
  float* keysT = ws + 1048576;       // 262144
  float* E     = ws + 1310720;       // 25600
  float* gib   = ws + 1336320;       // 3072
  float* gi    = ws + 1339392;       // 76800
  float* HC    = ws + 1416192;       // 51200
  float* Qt    = ws + 1467392;       // 25600
  float* VEC   = ws + 1492992;       // 25600
  float* ep    = ws + 1518592;       // 51200
  float* hx    = ep;                 // 2048 (aliases ep; hx dead before attn1 writes ep)

  hipMemsetAsync(hx, 0, 2048*4, stream);
  k_pre<<<868, 256, 0, stream>>>(Wih, qv, bih, ta, emb, gib, E);
  k_keys<<<dim3(64,4), 256, 0, stream>>>(qw, Wk, part);
  k_keys_red<<<256, 256, 0, stream>>>(part, bk, keysT);
  k_gemm_s2<1024,16><<<768, 256, 0, stream>>>(Wih + 1024, 2048, E, 1024, gib, gi, 3072, 25, 0);
  k_gru4<<<256, 256, 0, stream>>>(Whh, bhh, gi, dv, HC, hx);
  k_gemm_s2<1024,16><<<256, 256, 0, stream>>>(Wq, 1024, HC, 2048, bq, Qt, 1024, 25, 0);
  k_attn1<<<dim3(25,8), 256, 0, stream>>>(keysT, Qt, av, ep);
  k_attn2<<<25, 256, 0, stream>>>(ep, qw, HC);
  k_gemm_s2<2048,8><<<256, 256, 0, stream>>>(cW, 2048, HC, 2048, cb, VEC, 1024, 25, 1);
  k_gemm_big5<<<197, 256, 0, stream>>>(oW, VEC, ob, out + 25);
  k_lstat<<<dim3(25,8), 256, 0, stream>>>(out + 25, pm, ps, pa);
  k_lfin<<<1, 64, 0, stream>>>(pm, ps, pa, Lg, out);
  k_lsub<<<dim3(197,25), 256, 0, stream>>>(out + 25, Lg);
}

// Round 6
// 587.252 us; speedup vs baseline: 3.7949x; 1.0574x over previous
//
#include <hip/hip_runtime.h>
#include <math.h>

#define VOCAB 50257
#define EMB 1024
#define HD 1024
#define TRK 1024
#define LQ 256
#define BND 25

// ---------------- helpers ----------------
__device__ __forceinline__ float wred(float s){
  #pragma unroll
  for (int m = 32; m >= 1; m >>= 1) s += __shfl_xor(s, m, 64);
  return s;
}

// ---------------- K_pre: gi_base rows + embedding gather ----------------
__global__ __launch_bounds__(256) void k_pre(const float* __restrict__ Wih,
                                             const float* __restrict__ qv,
                                             const float* __restrict__ bih,
                                             const int*   __restrict__ ta,
                                             const float* __restrict__ emb,
                                             float* __restrict__ gib,
                                             float* __restrict__ E){
  int b = blockIdx.x, tid = threadIdx.x;
  if (b < 768){
    int w = tid >> 6, lane = tid & 63;
    int row = b*4 + w;
    const float* a = Wih + (size_t)row*2048;
    float s = 0.f;
    #pragma unroll
    for (int e = 0; e < 4; e++){
      int k = e*256 + lane*4;
      float4 av = *(const float4*)(a + k);
      float4 qr = *(const float4*)(qv + k);
      s += av.x*qr.x + av.y*qr.y + av.z*qr.z + av.w*qr.w;
    }
    s = wred(s);
    if (lane == 0) gib[row] = s + bih[row];
  } else {
    int g = (b - 768)*256 + tid;      // 0..25599
    int t = g >> 10, i = g & 1023;
    int idx = (t == 0) ? 0 : ta[t-1];
    E[g] = emb[(size_t)idx*EMB + i];
  }
}

// ---------------- K_keys: keysT[j][l] partials (k-split x4) ----------------
__global__ __launch_bounds__(256) void k_keys(const float* __restrict__ qw,
                                              const float* __restrict__ Wk,
                                              float* __restrict__ part){
  __shared__ float qt[64*256];
  int jb = blockIdx.x;                // 0..63 -> 16 j's each
  int ks = blockIdx.y;                // 0..3  -> k-chunk of 256
  int tid = threadIdx.x;
  int l = tid;
  float acc[16];
  #pragma unroll
  for (int j = 0; j < 16; j++) acc[j] = 0.f;

  for (int kt = 0; kt < 4; kt++){
    int kb = ks*256 + kt*64;
    __syncthreads();
    #pragma unroll
    for (int p = 0; p < 16; p++){
      int fidx = (p*256 + tid)*4;
      int kk = fidx & 63, ll = fidx >> 6;
      float4 v = *(const float4*)(qw + (size_t)ll*1024 + kb + kk);
      qt[(kk+0)*256 + (ll ^ ((kk+0)&31))] = v.x;
      qt[(kk+1)*256 + (ll ^ ((kk+1)&31))] = v.y;
      qt[(kk+2)*256 + (ll ^ ((kk+2)&31))] = v.z;
      qt[(kk+3)*256 + (ll ^ ((kk+3)&31))] = v.w;
    }
    __syncthreads();
    #pragma unroll
    for (int s = 0; s < 4; s++){
      float qr[16];
      #pragma unroll
      for (int q = 0; q < 16; q++){
        int k = s*16 + q;
        qr[q] = qt[k*256 + (l ^ (k&31))];
      }
      #pragma unroll
      for (int j = 0; j < 16; j++){
        const float* wr = Wk + (size_t)(jb*16 + j)*1024 + kb + s*16;
        #pragma unroll
        for (int q4 = 0; q4 < 4; q4++){
          float4 wv = *(const float4*)(wr + q4*4);
          acc[j] += qr[q4*4+0]*wv.x + qr[q4*4+1]*wv.y
                  + qr[q4*4+2]*wv.z + qr[q4*4+3]*wv.w;
        }
      }
    }
  }
  #pragma unroll
  for (int j = 0; j < 16; j++)
    part[((size_t)ks*1024 + jb*16 + j)*256 + l] = acc[j];
}

// ---------------- K_keys_red: keysT = sum of 4 partials + bk[j] ----------------
__global__ __launch_bounds__(256) void k_keys_red(const float* __restrict__ part,
                                                  const float* __restrict__ bk,
                                                  float* __restrict__ keysT){
  int g = blockIdx.x*256 + threadIdx.x;   // 65536 threads * 4 floats
  int base = g*4;
  float4 s0 = *(const float4*)(part + base);
  float4 s1 = *(const float4*)(part + 262144 + base);
  float4 s2 = *(const float4*)(part + 524288 + base);
  float4 s3 = *(const float4*)(part + 786432 + base);
  float b = bk[base >> 8];
  float4 r;
  r.x = s0.x + s1.x + s2.x + s3.x + b;
  r.y = s0.y + s1.y + s2.y + s3.y + b;
  r.z = s0.z + s1.z + s2.z + s3.z + b;
  r.w = s0.w + s1.w + s2.w + s3.w + b;
  *(float4*)(keysT + base) = r;
}

// ---------------- K_gemm_s2: skinny GEMM, wave-per-row, chunked B staging ----------------
template<int K, int NCH>
__global__ __launch_bounds__(256) void k_gemm_s2(const float* __restrict__ A, int lda,
                                                 const float* __restrict__ B, int ldb,
                                                 const float* __restrict__ bias,
                                                 float* __restrict__ C,
                                                 int R, int N, int act){
  __shared__ float Bl[NCH*K];
  constexpr int KD4 = K/4;
  int tid = threadIdx.x, w = tid >> 6, lane = tid & 63;
  int row = blockIdx.x*4 + w;
  const float* a = A + (size_t)row*lda;
  float4 ar[K/256];
  #pragma unroll
  for (int e = 0; e < K/256; e++)
    ar[e] = *(const float4*)(a + e*256 + lane*4);
  float bs = bias[row];
  for (int c0 = 0; c0 < N; c0 += NCH){
    int nt = min(NCH, N - c0);
    __syncthreads();
    int total = nt*KD4;
    for (int i = tid; i < total; i += 256){
      int j = i/KD4, kk = i - j*KD4;
      *(float4*)&Bl[j*K + kk*4] = *(const float4*)(B + (size_t)(c0+j)*ldb + kk*4);
    }
    __syncthreads();
    for (int j = 0; j < nt; j++){
      float s = 0.f;
      #pragma unroll
      for (int e = 0; e < K/256; e++){
        float4 bv = *(const float4*)&Bl[j*K + e*256 + lane*4];
        s += ar[e].x*bv.x + ar[e].y*bv.y + ar[e].z*bv.z + ar[e].w*bv.w;
      }
      s = wred(s);
      if (lane == 0){
        float v = s + bs;
        if (act) v = tanhf(v);
        C[(size_t)(c0+j)*R + row] = v;
      }
    }
  }
}

// ---------------- K_gru4: 25 GRU steps; Whh in LDS; L3-atomic h exchange ----------------
__global__ __launch_bounds__(256, 2) void k_gru4(const float* __restrict__ Whh,
                                                 const float* __restrict__ bhh,
                                                 const float* __restrict__ gi,
                                                 const float* __restrict__ dv,
                                                 float* __restrict__ HC,
                                                 float* __restrict__ hx){
  __shared__ float Wl[12][1024];
  __shared__ float hbuf[1024];
  __shared__ float sres[12];
  int tid = threadIdx.x, w = tid >> 6, lane = tid & 63;
  int b = blockIdx.x;
  for (int i = tid; i < 3072; i += 256){
    int r = i >> 8, c = (i & 255)*4;
    int g = r >> 2, s = r & 3;
    *(float4*)&Wl[r][c] = *(const float4*)(Whh + (size_t)(g*1024 + b*4 + s)*1024 + c);
  }
  *(float4*)&hbuf[tid*4] = *(const float4*)(dv + tid*4);
  __syncthreads();

  for (int t = 0; t < BND; t++){
    float g0=0,g1=0,g2=0,bb0=0,bb1=0,bb2=0,hpown=0;
    if (tid < 4){
      int i = b*4 + tid;
      const float* gg = gi + (size_t)t*3072;
      g0 = gg[i]; g1 = gg[1024+i]; g2 = gg[2048+i];
      bb0 = bhh[i]; bb1 = bhh[1024+i]; bb2 = bhh[2048+i];
      hpown = hbuf[i];
    }
    float hv[16];
    #pragma unroll
    for (int e = 0; e < 4; e++){
      float4 v = *(const float4*)&hbuf[e*256 + lane*4];
      hv[e*4]=v.x; hv[e*4+1]=v.y; hv[e*4+2]=v.z; hv[e*4+3]=v.w;
    }
    #pragma unroll
    for (int j = 0; j < 3; j++){
      int r = w*3 + j;
      float a = 0.f;
      #pragma unroll
      for (int e = 0; e < 4; e++){
        float4 v = *(const float4*)&Wl[r][e*256 + lane*4];
        a += v.x*hv[e*4] + v.y*hv[e*4+1] + v.z*hv[e*4+2] + v.w*hv[e*4+3];
      }
      a = wred(a);
      if (lane == 0) sres[r] = a;
    }
    __syncthreads();
    if (tid < 4){
      int i = b*4 + tid;
      float ghr = sres[tid]   + bb0;
      float ghz = sres[4+tid] + bb1;
      float ghn = sres[8+tid] + bb2;
      float rr = 1.f/(1.f + expf(-(g0 + ghr)));
      float zz = 1.f/(1.f + expf(-(g1 + ghz)));
      float nn = tanhf(g2 + rr*ghn);
      float hnew = (1.f - zz)*nn + zz*hpown;
      HC[(size_t)t*2048 + i] = hnew;
      if (t < BND-1){
        __hip_atomic_store(hx + b*8 + tid, hnew, __ATOMIC_RELAXED, __HIP_MEMORY_SCOPE_AGENT);
        asm volatile("s_waitcnt vmcnt(0)" ::: "memory");
      }
    }
    if (t == BND-1) break;
    __syncthreads();
    if (tid == 0)
      __hip_atomic_store((int*)(hx + b*8 + 4), t+1, __ATOMIC_RELAXED, __HIP_MEMORY_SCOPE_AGENT);
    if (w == 0){
      for (;;){
        int f0 = __hip_atomic_load((const int*)(hx + (lane      )*8 + 4), __ATOMIC_RELAXED, __HIP_MEMORY_SCOPE_AGENT);
        int f1 = __hip_atomic_load((const int*)(hx + (64  + lane)*8 + 4), __ATOMIC_RELAXED, __HIP_MEMORY_SCOPE_AGENT);
        int f2 = __hip_atomic_load((const int*)(hx + (128 + lane)*8 + 4), __ATOMIC_RELAXED, __HIP_MEMORY_SCOPE_AGENT);
        int f3 = __hip_atomic_load((const int*)(hx + (192 + lane)*8 + 4), __ATOMIC_RELAXED, __HIP_MEMORY_SCOPE_AGENT);
        if (min(min(f0,f1),min(f2,f3)) >= t+1) break;
        __builtin_amdgcn_s_sleep(2);
      }
      #pragma unroll
      for (int q = 0; q < 4; q++){
        float d0 = __hip_atomic_load(hx + (q*64 + lane)*8 + 0, __ATOMIC_RELAXED, __HIP_MEMORY_SCOPE_AGENT);
        float d1 = __hip_atomic_load(hx + (q*64 + lane)*8 + 1, __ATOMIC_RELAXED, __HIP_MEMORY_SCOPE_AGENT);
        float d2 = __hip_atomic_load(hx + (q*64 + lane)*8 + 2, __ATOMIC_RELAXED, __HIP_MEMORY_SCOPE_AGENT);
        float d3 = __hip_atomic_load(hx + (q*64 + lane)*8 + 3, __ATOMIC_RELAXED, __HIP_MEMORY_SCOPE_AGENT);
        hbuf[q*256 + lane*4 + 0] = d0;
        hbuf[q*256 + lane*4 + 1] = d1;
        hbuf[q*256 + lane*4 + 2] = d2;
        hbuf[q*256 + lane*4 + 3] = d3;
      }
    }
    __syncthreads();
  }
}

// ---------------- K_attn1: e partials over j-chunks ----------------
__global__ __launch_bounds__(256) void k_attn1(const float* __restrict__ keysT,
                                               const float* __restrict__ Qt,
                                               const float* __restrict__ av,
                                               float* __restrict__ epart){
  int t = blockIdx.x, jc = blockIdx.y;
  int l = threadIdx.x;
  const float* q = Qt + (size_t)t*1024;
  float acc = 0.f;
  for (int j = jc*128; j < jc*128 + 128; j++){
    float kv = keysT[(size_t)j*256 + l];
    acc += tanhf(kv + q[j]) * av[j];
  }
  epart[((size_t)t*8 + jc)*256 + l] = acc;
}

// ---------------- K_attn2: softmax over l + ctx = w @ qw ----------------
__global__ __launch_bounds__(256) void k_attn2(const float* __restrict__ epart,
                                               const float* __restrict__ qw,
                                               float* __restrict__ HC){
  __shared__ float red[256];
  __shared__ float sw[256];
  int t = blockIdx.x, tid = threadIdx.x;
  float e = 0.f;
  for (int jc = 0; jc < 8; jc++) e += epart[((size_t)t*8 + jc)*256 + tid];
  red[tid] = e; __syncthreads();
  for (int s = 128; s > 0; s >>= 1){
    if (tid < s) red[tid] = fmaxf(red[tid], red[tid+s]);
    __syncthreads();
  }
  float m = red[0]; __syncthreads();
  float wv = expf(e - m);
  red[tid] = wv; __syncthreads();
  for (int s = 128; s > 0; s >>= 1){
    if (tid < s) red[tid] += red[tid+s];
    __syncthreads();
  }
  float inv = 1.f/red[0];
  sw[tid] = wv*inv; __syncthreads();
  float4 c = make_float4(0.f,0.f,0.f,0.f);
  const float* qp = qw + tid*4;
  for (int ll = 0; ll < 256; ll++){
    float wl = sw[ll];
    float4 v = *(const float4*)(qp + (size_t)ll*1024);
    c.x += wl*v.x; c.y += wl*v.y; c.z += wl*v.z; c.w += wl*v.w;
  }
  *(float4*)(HC + (size_t)t*2048 + 1024 + tid*4) = c;
}

// ---------------- K_gemm_big6: 50257x1024 @ 1024x25, quarter-split waves ----------------
// 197 blocks x 1024 thr. Thread (rl, q=tid>>8): row = b*256+rl, k-quarter q (256 floats).
// 16 waves/CU (4/SIMD, VGPR budget 128, ~70 live -> no spill). Per-thread: 64 A-float4,
// 400 B-loads (B-quarter 25KB, L1/L2-hot). Cross-quarter reduce via LDS (conflict-free
// 25-stride), q0 adds bias + writes C.
__global__ __launch_bounds__(1024, 4) void k_gemm_big6(const float* __restrict__ A,
                                                       const float* __restrict__ B,
                                                       const float* __restrict__ bias,
                                                       float* __restrict__ C){
  __shared__ float sred[3*256*25];    // 76.8 KB
  int tid = threadIdx.x;
  int rl = tid & 255;
  int q  = tid >> 8;
  int row = blockIdx.x*256 + rl;
  int rowc = (row < VOCAB) ? row : (VOCAB-1);
  const float* ap = A + (size_t)rowc*1024 + q*256;
  const float* bp = B + q*256;

  float acc[25];
  #pragma unroll
  for (int t = 0; t < 25; t++) acc[t] = 0.f;

  float4 a0 = *(const float4*)(ap + 0);
  float4 a1 = *(const float4*)(ap + 4);
  float4 a2 = *(const float4*)(ap + 8);
  float4 a3 = *(const float4*)(ap + 12);
  for (int kb = 0; kb < 256; kb += 16){
    float4 n0, n1, n2, n3;
    if (kb + 16 < 256){
      n0 = *(const float4*)(ap + kb + 16);
      n1 = *(const float4*)(ap + kb + 20);
      n2 = *(const float4*)(ap + kb + 24);
      n3 = *(const float4*)(ap + kb + 28);
    }
    #pragma unroll
    for (int t = 0; t < 25; t++){
      const float* bt = bp + t*1024 + kb;
      float4 b0 = *(const float4*)(bt + 0);
      float4 b1 = *(const float4*)(bt + 4);
      float4 b2 = *(const float4*)(bt + 8);
      float4 b3 = *(const float4*)(bt + 12);
      acc[t] += a0.x*b0.x + a0.y*b0.y + a0.z*b0.z + a0.w*b0.w
              + a1.x*b1.x + a1.y*b1.y + a1.z*b1.z + a1.w*b1.w
              + a2.x*b2.x + a2.y*b2.y + a2.z*b2.z + a2.w*b2.w
              + a3.x*b3.x + a3.y*b3.y + a3.z*b3.z + a3.w*b3.w;
    }
    a0 = n0; a1 = n1; a2 = n2; a3 = n3;
  }
  if (q > 0){
    #pragma unroll
    for (int t = 0; t < 25; t++)
      sred[(q-1)*6400 + rl*25 + t] = acc[t];
  }
  __syncthreads();
  if (q == 0 && row < VOCAB){
    float bs = bias[row];
    #pragma unroll
    for (int t = 0; t < 25; t++){
      float s = acc[t] + bs
              + sred[        rl*25 + t]
              + sred[ 6400 + rl*25 + t]
              + sred[12800 + rl*25 + t];
      C[(size_t)t*VOCAB + row] = s;
    }
  }
}

// ---------------- K_lstat: per (t, chunk) online max/argmax/sumexp ----------------
__global__ __launch_bounds__(256) void k_lstat(const float* __restrict__ C,
                                               float* __restrict__ pm,
                                               float* __restrict__ ps,
                                               int*   __restrict__ pa){
  __shared__ float sm[256], ss[256];
  __shared__ int   sa[256];
  int t = blockIdx.x, c = blockIdx.y, tid = threadIdx.x;
  int r0 = c*6283, r1 = min(r0 + 6283, VOCAB);
  const float* p = C + (size_t)t*VOCAB;
  float m = -3.4e38f, s = 0.f; int arg = r0;
  for (int r = r0 + tid; r < r1; r += 256){
    float x = p[r];
    if (x > m){ s = s*expf(m - x) + 1.f; m = x; arg = r; }
    else       s += expf(x - m);
  }
  sm[tid] = m; ss[tid] = s; sa[tid] = arg; __syncthreads();
  for (int st = 128; st > 0; st >>= 1){
    if (tid < st){
      float m1 = sm[tid], s1 = ss[tid]; int a1 = sa[tid];
      float m2 = sm[tid+st], s2 = ss[tid+st]; int a2 = sa[tid+st];
      if (m2 > m1){ sm[tid] = m2; ss[tid] = s2 + s1*expf(m1 - m2); sa[tid] = a2; }
      else if (m2 == m1){ ss[tid] = s1 + s2; sa[tid] = min(a1, a2); }
      else { ss[tid] = s1 + s2*expf(m2 - m1); }
    }
    __syncthreads();
  }
  if (tid == 0){ pm[t*8 + c] = sm[0]; ps[t*8 + c] = ss[0]; pa[t*8 + c] = sa[0]; }
}

// ---------------- K_lfin: combine 8 chunks -> Lg[t], out[t]=argmax ----------------
__global__ void k_lfin(const float* __restrict__ pm, const float* __restrict__ ps,
                       const int* __restrict__ pa, float* __restrict__ Lg,
                       float* __restrict__ out){
  int t = threadIdx.x;
  if (t < 25){
    float M = pm[t*8], S = ps[t*8]; int A = pa[t*8];
    for (int c = 1; c < 8; c++){
      float m2 = pm[t*8+c], s2 = ps[t*8+c]; int a2 = pa[t*8+c];
      if (m2 > M){ S = s2 + S*expf(M - m2); M = m2; A = a2; }
      else if (m2 == M){ S += s2; A = min(A, a2); }
      else S += s2*expf(m2 - M);
    }
    Lg[t] = logf(S) + M;
    out[t] = (float)A;
  }
}

// ---------------- K_lsub: p -= Lg[t] ----------------
__global__ __launch_bounds__(256) void k_lsub(float* __restrict__ C,
                                              const float* __restrict__ Lg){
  int t = blockIdx.y;
  int r = blockIdx.x*256 + threadIdx.x;
  if (r < VOCAB) C[(size_t)t*VOCAB + r] -= Lg[t];
}

// ---------------- launch ----------------
extern "C" void kernel_launch(void* const* d_in, const int* in_sizes, int n_in,
                              void* d_out, int out_size, void* d_ws, size_t ws_size,
                              hipStream_t stream){
  const float* qw  = (const float*)d_in[0];
  const float* qv  = (const float*)d_in[1];
  const float* dv  = (const float*)d_in[2];
  const int*   ta  = (const int*)d_in[3];
  const float* emb = (const float*)d_in[4];
  const float* Wih = (const float*)d_in[5];
  const float* Whh = (const float*)d_in[6];
  const float* bih = (const float*)d_in[7];
  const float* bhh = (const float*)d_in[8];
  const float* Wq  = (const float*)d_in[9];
  const float* bq  = (const float*)d_in[10];
  const float* Wk  = (const float*)d_in[11];
  const float* bk  = (const float*)d_in[12];
  const float* av  = (const float*)d_in[13];
  const float* cW  = (const float*)d_in[14];
  const float* cb  = (const float*)d_in[15];
  const float* oW  = (const float*)d_in[16];
  const float* ob  = (const float*)d_in[17];
  float* out = (float*)d_out;
  float* ws  = (float*)d_ws;

  float* part  = ws;                 // 1048576 (dead after keys_red)
  float* pm    = ws;                 // 200   (aliases part; used post-big6)
  float* ps    = ws + 256;           // 200
  int*   pa    = (int*)(ws + 512);   // 200
  float* Lg    = ws + 768;           // 25
  float* keysT = ws + 1048576;       // 262144
  float* E     = ws + 1310720;       // 25600
  float* gib   = ws + 1336320;       // 3072
  float* gi    = ws + 1339392;       // 76800
  float* HC    = ws + 1416192;       // 51200
  float* Qt    = ws + 1467392;       // 25600
  float* VEC   = ws + 1492992;       // 25600
  float* ep    = ws + 1518592;       // 51200
  float* hx    = ep;                 // 2048 (aliases ep; hx dead before attn1 writes ep)

  hipMemsetAsync(hx, 0, 2048*4, stream);
  k_pre<<<868, 256, 0, stream>>>(Wih, qv, bih, ta, emb, gib, E);
  k_keys<<<dim3(64,4), 256, 0, stream>>>(qw, Wk, part);
  k_keys_red<<<256, 256, 0, stream>>>(part, bk, keysT);
  k_gemm_s2<1024,16><<<768, 256, 0, stream>>>(Wih + 1024, 2048, E, 1024, gib, gi, 3072, 25, 0);
  k_gru4<<<256, 256, 0, stream>>>(Whh, bhh, gi, dv, HC, hx);
  k_gemm_s2<1024,16><<<256, 256, 0, stream>>>(Wq, 1024, HC, 2048, bq, Qt, 1024, 25, 0);
  k_attn1<<<dim3(25,8), 256, 0, stream>>>(keysT, Qt, av, ep);
  k_attn2<<<25, 256, 0, stream>>>(ep, qw, HC);
  k_gemm_s2<2048,8><<<256, 256, 0, stream>>>(cW, 2048, HC, 2048, cb, VEC, 1024, 25, 1);
  k_gemm_big6<<<197, 1024, 0, stream>>>(oW, VEC, ob, out + 25);
  k_lstat<<<dim3(25,8), 256, 0, stream>>>(out + 25, pm, ps, pa);
  k_lfin<<<1, 64, 0, stream>>>(pm, ps, pa, Lg, out);
  k_lsub<<<dim3(197,25), 256, 0, stream>>>(out + 25, Lg);
}

// Round 7
// 464.794 us; speedup vs baseline: 4.7948x; 1.2635x over previous
//
#include <hip/hip_runtime.h>
#include <math.h>

#define VOCAB 50257
#define EMB 1024
#define HD 1024
#define TRK 1024
#define LQ 256
#define BND 25

// ---------------- helpers ----------------
__device__ __forceinline__ float wred(float s){
  #pragma unroll
  for (int m = 32; m >= 1; m >>= 1) s += __shfl_xor(s, m, 64);
  return s;
}

// ---------------- K_pre: gi_base rows + embedding gather ----------------
__global__ __launch_bounds__(256) void k_pre(const float* __restrict__ Wih,
                                             const float* __restrict__ qv,
                                             const float* __restrict__ bih,
                                             const int*   __restrict__ ta,
                                             const float* __restrict__ emb,
                                             float* __restrict__ gib,
                                             float* __restrict__ E){
  int b = blockIdx.x, tid = threadIdx.x;
  if (b < 768){
    int w = tid >> 6, lane = tid & 63;
    int row = b*4 + w;
    const float* a = Wih + (size_t)row*2048;
    float s = 0.f;
    #pragma unroll
    for (int e = 0; e < 4; e++){
      int k = e*256 + lane*4;
      float4 av = *(const float4*)(a + k);
      float4 qr = *(const float4*)(qv + k);
      s += av.x*qr.x + av.y*qr.y + av.z*qr.z + av.w*qr.w;
    }
    s = wred(s);
    if (lane == 0) gib[row] = s + bih[row];
  } else {
    int g = (b - 768)*256 + tid;      // 0..25599
    int t = g >> 10, i = g & 1023;
    int idx = (t == 0) ? 0 : ta[t-1];
    E[g] = emb[(size_t)idx*EMB + i];
  }
}

// ---------------- K_keys: keysT[j][l] partials (k-split x4) ----------------
__global__ __launch_bounds__(256) void k_keys(const float* __restrict__ qw,
                                              const float* __restrict__ Wk,
                                              float* __restrict__ part){
  __shared__ float qt[64*256];
  int jb = blockIdx.x;                // 0..63 -> 16 j's each
  int ks = blockIdx.y;                // 0..3  -> k-chunk of 256
  int tid = threadIdx.x;
  int l = tid;
  float acc[16];
  #pragma unroll
  for (int j = 0; j < 16; j++) acc[j] = 0.f;

  for (int kt = 0; kt < 4; kt++){
    int kb = ks*256 + kt*64;
    __syncthreads();
    #pragma unroll
    for (int p = 0; p < 16; p++){
      int fidx = (p*256 + tid)*4;
      int kk = fidx & 63, ll = fidx >> 6;
      float4 v = *(const float4*)(qw + (size_t)ll*1024 + kb + kk);
      qt[(kk+0)*256 + (ll ^ ((kk+0)&31))] = v.x;
      qt[(kk+1)*256 + (ll ^ ((kk+1)&31))] = v.y;
      qt[(kk+2)*256 + (ll ^ ((kk+2)&31))] = v.z;
      qt[(kk+3)*256 + (ll ^ ((kk+3)&31))] = v.w;
    }
    __syncthreads();
    #pragma unroll
    for (int s = 0; s < 4; s++){
      float qr[16];
      #pragma unroll
      for (int q = 0; q < 16; q++){
        int k = s*16 + q;
        qr[q] = qt[k*256 + (l ^ (k&31))];
      }
      #pragma unroll
      for (int j = 0; j < 16; j++){
        const float* wr = Wk + (size_t)(jb*16 + j)*1024 + kb + s*16;
        #pragma unroll
        for (int q4 = 0; q4 < 4; q4++){
          float4 wv = *(const float4*)(wr + q4*4);
          acc[j] += qr[q4*4+0]*wv.x + qr[q4*4+1]*wv.y
                  + qr[q4*4+2]*wv.z + qr[q4*4+3]*wv.w;
        }
      }
    }
  }
  #pragma unroll
  for (int j = 0; j < 16; j++)
    part[((size_t)ks*1024 + jb*16 + j)*256 + l] = acc[j];
}

// ---------------- K_keys_red: keysT = sum of 4 partials + bk[j] ----------------
__global__ __launch_bounds__(256) void k_keys_red(const float* __restrict__ part,
                                                  const float* __restrict__ bk,
                                                  float* __restrict__ keysT){
  int g = blockIdx.x*256 + threadIdx.x;   // 65536 threads * 4 floats
  int base = g*4;
  float4 s0 = *(const float4*)(part + base);
  float4 s1 = *(const float4*)(part + 262144 + base);
  float4 s2 = *(const float4*)(part + 524288 + base);
  float4 s3 = *(const float4*)(part + 786432 + base);
  float b = bk[base >> 8];
  float4 r;
  r.x = s0.x + s1.x + s2.x + s3.x + b;
  r.y = s0.y + s1.y + s2.y + s3.y + b;
  r.z = s0.z + s1.z + s2.z + s3.z + b;
  r.w = s0.w + s1.w + s2.w + s3.w + b;
  *(float4*)(keysT + base) = r;
}

// ---------------- K_gemm_s2: skinny GEMM, wave-per-row, chunked B staging ----------------
template<int K, int NCH>
__global__ __launch_bounds__(256) void k_gemm_s2(const float* __restrict__ A, int lda,
                                                 const float* __restrict__ B, int ldb,
                                                 const float* __restrict__ bias,
                                                 float* __restrict__ C,
                                                 int R, int N, int act){
  __shared__ float Bl[NCH*K];
  constexpr int KD4 = K/4;
  int tid = threadIdx.x, w = tid >> 6, lane = tid & 63;
  int row = blockIdx.x*4 + w;
  const float* a = A + (size_t)row*lda;
  float4 ar[K/256];
  #pragma unroll
  for (int e = 0; e < K/256; e++)
    ar[e] = *(const float4*)(a + e*256 + lane*4);
  float bs = bias[row];
  for (int c0 = 0; c0 < N; c0 += NCH){
    int nt = min(NCH, N - c0);
    __syncthreads();
    int total = nt*KD4;
    for (int i = tid; i < total; i += 256){
      int j = i/KD4, kk = i - j*KD4;
      *(float4*)&Bl[j*K + kk*4] = *(const float4*)(B + (size_t)(c0+j)*ldb + kk*4);
    }
    __syncthreads();
    for (int j = 0; j < nt; j++){
      float s = 0.f;
      #pragma unroll
      for (int e = 0; e < K/256; e++){
        float4 bv = *(const float4*)&Bl[j*K + e*256 + lane*4];
        s += ar[e].x*bv.x + ar[e].y*bv.y + ar[e].z*bv.z + ar[e].w*bv.w;
      }
      s = wred(s);
      if (lane == 0){
        float v = s + bs;
        if (act) v = tanhf(v);
        C[(size_t)(c0+j)*R + row] = v;
      }
    }
  }
}

// ---------------- K_gru4: 25 GRU steps; Whh in LDS; L3-atomic h exchange ----------------
__global__ __launch_bounds__(256, 2) void k_gru4(const float* __restrict__ Whh,
                                                 const float* __restrict__ bhh,
                                                 const float* __restrict__ gi,
                                                 const float* __restrict__ dv,
                                                 float* __restrict__ HC,
                                                 float* __restrict__ hx){
  __shared__ float Wl[12][1024];
  __shared__ float hbuf[1024];
  __shared__ float sres[12];
  int tid = threadIdx.x, w = tid >> 6, lane = tid & 63;
  int b = blockIdx.x;
  for (int i = tid; i < 3072; i += 256){
    int r = i >> 8, c = (i & 255)*4;
    int g = r >> 2, s = r & 3;
    *(float4*)&Wl[r][c] = *(const float4*)(Whh + (size_t)(g*1024 + b*4 + s)*1024 + c);
  }
  *(float4*)&hbuf[tid*4] = *(const float4*)(dv + tid*4);
  __syncthreads();

  for (int t = 0; t < BND; t++){
    float g0=0,g1=0,g2=0,bb0=0,bb1=0,bb2=0,hpown=0;
    if (tid < 4){
      int i = b*4 + tid;
      const float* gg = gi + (size_t)t*3072;
      g0 = gg[i]; g1 = gg[1024+i]; g2 = gg[2048+i];
      bb0 = bhh[i]; bb1 = bhh[1024+i]; bb2 = bhh[2048+i];
      hpown = hbuf[i];
    }
    float hv[16];
    #pragma unroll
    for (int e = 0; e < 4; e++){
      float4 v = *(const float4*)&hbuf[e*256 + lane*4];
      hv[e*4]=v.x; hv[e*4+1]=v.y; hv[e*4+2]=v.z; hv[e*4+3]=v.w;
    }
    #pragma unroll
    for (int j = 0; j < 3; j++){
      int r = w*3 + j;
      float a = 0.f;
      #pragma unroll
      for (int e = 0; e < 4; e++){
        float4 v = *(const float4*)&Wl[r][e*256 + lane*4];
        a += v.x*hv[e*4] + v.y*hv[e*4+1] + v.z*hv[e*4+2] + v.w*hv[e*4+3];
      }
      a = wred(a);
      if (lane == 0) sres[r] = a;
    }
    __syncthreads();
    if (tid < 4){
      int i = b*4 + tid;
      float ghr = sres[tid]   + bb0;
      float ghz = sres[4+tid] + bb1;
      float ghn = sres[8+tid] + bb2;
      float rr = 1.f/(1.f + expf(-(g0 + ghr)));
      float zz = 1.f/(1.f + expf(-(g1 + ghz)));
      float nn = tanhf(g2 + rr*ghn);
      float hnew = (1.f - zz)*nn + zz*hpown;
      HC[(size_t)t*2048 + i] = hnew;
      if (t < BND-1){
        __hip_atomic_store(hx + b*8 + tid, hnew, __ATOMIC_RELAXED, __HIP_MEMORY_SCOPE_AGENT);
        asm volatile("s_waitcnt vmcnt(0)" ::: "memory");
      }
    }
    if (t == BND-1) break;
    __syncthreads();
    if (tid == 0)
      __hip_atomic_store((int*)(hx + b*8 + 4), t+1, __ATOMIC_RELAXED, __HIP_MEMORY_SCOPE_AGENT);
    if (w == 0){
      for (;;){
        int f0 = __hip_atomic_load((const int*)(hx + (lane      )*8 + 4), __ATOMIC_RELAXED, __HIP_MEMORY_SCOPE_AGENT);
        int f1 = __hip_atomic_load((const int*)(hx + (64  + lane)*8 + 4), __ATOMIC_RELAXED, __HIP_MEMORY_SCOPE_AGENT);
        int f2 = __hip_atomic_load((const int*)(hx + (128 + lane)*8 + 4), __ATOMIC_RELAXED, __HIP_MEMORY_SCOPE_AGENT);
        int f3 = __hip_atomic_load((const int*)(hx + (192 + lane)*8 + 4), __ATOMIC_RELAXED, __HIP_MEMORY_SCOPE_AGENT);
        if (min(min(f0,f1),min(f2,f3)) >= t+1) break;
        __builtin_amdgcn_s_sleep(2);
      }
      #pragma unroll
      for (int q = 0; q < 4; q++){
        float d0 = __hip_atomic_load(hx + (q*64 + lane)*8 + 0, __ATOMIC_RELAXED, __HIP_MEMORY_SCOPE_AGENT);
        float d1 = __hip_atomic_load(hx + (q*64 + lane)*8 + 1, __ATOMIC_RELAXED, __HIP_MEMORY_SCOPE_AGENT);
        float d2 = __hip_atomic_load(hx + (q*64 + lane)*8 + 2, __ATOMIC_RELAXED, __HIP_MEMORY_SCOPE_AGENT);
        float d3 = __hip_atomic_load(hx + (q*64 + lane)*8 + 3, __ATOMIC_RELAXED, __HIP_MEMORY_SCOPE_AGENT);
        hbuf[q*256 + lane*4 + 0] = d0;
        hbuf[q*256 + lane*4 + 1] = d1;
        hbuf[q*256 + lane*4 + 2] = d2;
        hbuf[q*256 + lane*4 + 3] = d3;
      }
    }
    __syncthreads();
  }
}

// ---------------- K_attn1: e partials over j-chunks ----------------
__global__ __launch_bounds__(256) void k_attn1(const float* __restrict__ keysT,
                                               const float* __restrict__ Qt,
                                               const float* __restrict__ av,
                                               float* __restrict__ epart){
  int t = blockIdx.x, jc = blockIdx.y;
  int l = threadIdx.x;
  const float* q = Qt + (size_t)t*1024;
  float acc = 0.f;
  for (int j = jc*128; j < jc*128 + 128; j++){
    float kv = keysT[(size_t)j*256 + l];
    acc += tanhf(kv + q[j]) * av[j];
  }
  epart[((size_t)t*8 + jc)*256 + l] = acc;
}

// ---------------- K_attn2: softmax over l + ctx = w @ qw ----------------
__global__ __launch_bounds__(256) void k_attn2(const float* __restrict__ epart,
                                               const float* __restrict__ qw,
                                               float* __restrict__ HC){
  __shared__ float red[256];
  __shared__ float sw[256];
  int t = blockIdx.x, tid = threadIdx.x;
  float e = 0.f;
  for (int jc = 0; jc < 8; jc++) e += epart[((size_t)t*8 + jc)*256 + tid];
  red[tid] = e; __syncthreads();
  for (int s = 128; s > 0; s >>= 1){
    if (tid < s) red[tid] = fmaxf(red[tid], red[tid+s]);
    __syncthreads();
  }
  float m = red[0]; __syncthreads();
  float wv = expf(e - m);
  red[tid] = wv; __syncthreads();
  for (int s = 128; s > 0; s >>= 1){
    if (tid < s) red[tid] += red[tid+s];
    __syncthreads();
  }
  float inv = 1.f/red[0];
  sw[tid] = wv*inv; __syncthreads();
  float4 c = make_float4(0.f,0.f,0.f,0.f);
  const float* qp = qw + tid*4;
  for (int ll = 0; ll < 256; ll++){
    float wl = sw[ll];
    float4 v = *(const float4*)(qp + (size_t)ll*1024);
    c.x += wl*v.x; c.y += wl*v.y; c.z += wl*v.z; c.w += wl*v.w;
  }
  *(float4*)(HC + (size_t)t*2048 + 1024 + tid*4) = c;
}

// ---------------- K_gemm_big7: 50257x1024 @ 1024x25, B fully in LDS ----------------
// 197 blocks x 1024 thr. Thread (rl, q=tid>>8): row = b*256+rl, k-quarter q.
// B staged in LDS (100 KB, one co-op load); inner reads are wave-uniform
// ds_read_b128 broadcasts -> no L1 thrash, no L2 latency chains. A streams
// from HBM with 1-deep kb prefetch (compute/iter ~1200cy > 900cy HBM latency).
// Cross-quarter reduction aliases the B LDS buffer after a sync.
__global__ __launch_bounds__(1024, 4) void k_gemm_big7(const float* __restrict__ A,
                                                       const float* __restrict__ B,
                                                       const float* __restrict__ bias,
                                                       float* __restrict__ C){
  __shared__ float Bl[4*6400];        // 100 KB: quarter q -> Bl[q*6400 + t*256 + k]
  int tid = threadIdx.x;
  int rl = tid & 255;
  int q  = tid >> 8;
  int row = blockIdx.x*256 + rl;
  int rowc = (row < VOCAB) ? row : (VOCAB-1);
  const float* ap = A + (size_t)rowc*1024 + q*256;
  float* bq = Bl + q*6400;

  // stage B quarter: 1600 float4 per 256-thread quarter-group
  for (int i = rl; i < 1600; i += 256){
    int t = i >> 6, kk = (i & 63)*4;
    *(float4*)&bq[t*256 + kk] = *(const float4*)(B + (size_t)t*1024 + q*256 + kk);
  }
  float4 a0 = *(const float4*)(ap + 0);
  float4 a1 = *(const float4*)(ap + 4);
  float4 a2 = *(const float4*)(ap + 8);
  float4 a3 = *(const float4*)(ap + 12);
  __syncthreads();

  float acc[25];
  #pragma unroll
  for (int t = 0; t < 25; t++) acc[t] = 0.f;

  for (int kb = 0; kb < 256; kb += 16){
    float4 n0, n1, n2, n3;
    if (kb + 16 < 256){
      n0 = *(const float4*)(ap + kb + 16);
      n1 = *(const float4*)(ap + kb + 20);
      n2 = *(const float4*)(ap + kb + 24);
      n3 = *(const float4*)(ap + kb + 28);
    }
    #pragma unroll
    for (int t = 0; t < 25; t++){
      const float* bt = bq + t*256 + kb;
      float4 b0 = *(const float4*)(bt + 0);
      float4 b1 = *(const float4*)(bt + 4);
      float4 b2 = *(const float4*)(bt + 8);
      float4 b3 = *(const float4*)(bt + 12);
      acc[t] += a0.x*b0.x + a0.y*b0.y + a0.z*b0.z + a0.w*b0.w
              + a1.x*b1.x + a1.y*b1.y + a1.z*b1.z + a1.w*b1.w
              + a2.x*b2.x + a2.y*b2.y + a2.z*b2.z + a2.w*b2.w
              + a3.x*b3.x + a3.y*b3.y + a3.z*b3.z + a3.w*b3.w;
    }
    a0 = n0; a1 = n1; a2 = n2; a3 = n3;
  }
  __syncthreads();                    // all B reads done; Bl reusable
  if (q > 0){
    #pragma unroll
    for (int t = 0; t < 25; t++)
      Bl[(q-1)*6400 + rl*25 + t] = acc[t];
  }
  __syncthreads();
  if (q == 0 && row < VOCAB){
    float bs = bias[row];
    #pragma unroll
    for (int t = 0; t < 25; t++){
      float s = acc[t] + bs
              + Bl[        rl*25 + t]
              + Bl[ 6400 + rl*25 + t]
              + Bl[12800 + rl*25 + t];
      C[(size_t)t*VOCAB + row] = s;
    }
  }
}

// ---------------- K_lstat: per (t, chunk) online max/argmax/sumexp ----------------
__global__ __launch_bounds__(256) void k_lstat(const float* __restrict__ C,
                                               float* __restrict__ pm,
                                               float* __restrict__ ps,
                                               int*   __restrict__ pa){
  __shared__ float sm[256], ss[256];
  __shared__ int   sa[256];
  int t = blockIdx.x, c = blockIdx.y, tid = threadIdx.x;
  int r0 = c*6283, r1 = min(r0 + 6283, VOCAB);
  const float* p = C + (size_t)t*VOCAB;
  float m = -3.4e38f, s = 0.f; int arg = r0;
  for (int r = r0 + tid; r < r1; r += 256){
    float x = p[r];
    if (x > m){ s = s*expf(m - x) + 1.f; m = x; arg = r; }
    else       s += expf(x - m);
  }
  sm[tid] = m; ss[tid] = s; sa[tid] = arg; __syncthreads();
  for (int st = 128; st > 0; st >>= 1){
    if (tid < st){
      float m1 = sm[tid], s1 = ss[tid]; int a1 = sa[tid];
      float m2 = sm[tid+st], s2 = ss[tid+st]; int a2 = sa[tid+st];
      if (m2 > m1){ sm[tid] = m2; ss[tid] = s2 + s1*expf(m1 - m2); sa[tid] = a2; }
      else if (m2 == m1){ ss[tid] = s1 + s2; sa[tid] = min(a1, a2); }
      else { ss[tid] = s1 + s2*expf(m2 - m1); }
    }
    __syncthreads();
  }
  if (tid == 0){ pm[t*8 + c] = sm[0]; ps[t*8 + c] = ss[0]; pa[t*8 + c] = sa[0]; }
}

// ---------------- K_lfin: combine 8 chunks -> Lg[t], out[t]=argmax ----------------
__global__ void k_lfin(const float* __restrict__ pm, const float* __restrict__ ps,
                       const int* __restrict__ pa, float* __restrict__ Lg,
                       float* __restrict__ out){
  int t = threadIdx.x;
  if (t < 25){
    float M = pm[t*8], S = ps[t*8]; int A = pa[t*8];
    for (int c = 1; c < 8; c++){
      float m2 = pm[t*8+c], s2 = ps[t*8+c]; int a2 = pa[t*8+c];
      if (m2 > M){ S = s2 + S*expf(M - m2); M = m2; A = a2; }
      else if (m2 == M){ S += s2; A = min(A, a2); }
      else S += s2*expf(m2 - M);
    }
    Lg[t] = logf(S) + M;
    out[t] = (float)A;
  }
}

// ---------------- K_lsub: p -= Lg[t] ----------------
__global__ __launch_bounds__(256) void k_lsub(float* __restrict__ C,
                                              const float* __restrict__ Lg){
  int t = blockIdx.y;
  int r = blockIdx.x*256 + threadIdx.x;
  if (r < VOCAB) C[(size_t)t*VOCAB + r] -= Lg[t];
}

// ---------------- launch ----------------
extern "C" void kernel_launch(void* const* d_in, const int* in_sizes, int n_in,
                              void* d_out, int out_size, void* d_ws, size_t ws_size,
                              hipStream_t stream){
  const float* qw  = (const float*)d_in[0];
  const float* qv  = (const float*)d_in[1];
  const float* dv  = (const float*)d_in[2];
  const int*   ta  = (const int*)d_in[3];
  const float* emb = (const float*)d_in[4];
  const float* Wih = (const float*)d_in[5];
  const float* Whh = (const float*)d_in[6];
  const float* bih = (const float*)d_in[7];
  const float* bhh = (const float*)d_in[8];
  const float* Wq  = (const float*)d_in[9];
  const float* bq  = (const float*)d_in[10];
  const float* Wk  = (const float*)d_in[11];
  const float* bk  = (const float*)d_in[12];
  const float* av  = (const float*)d_in[13];
  const float* cW  = (const float*)d_in[14];
  const float* cb  = (const float*)d_in[15];
  const float* oW  = (const float*)d_in[16];
  const float* ob  = (const float*)d_in[17];
  float* out = (float*)d_out;
  float* ws  = (float*)d_ws;

  float* part  = ws;                 // 1048576 (dead after keys_red)
  float* pm    = ws;                 // 200   (aliases part; used post-big7)
  float* ps    = ws + 256;           // 200
  int*   pa    = (int*)(ws + 512);   // 200
  float* Lg    = ws + 768;           // 25
  float* keysT = ws + 1048576;       // 262144
  float* E     = ws + 1310720;       // 25600
  float* gib   = ws + 1336320;       // 3072
  float* gi    = ws + 1339392;       // 76800
  float* HC    = ws + 1416192;       // 51200
  float* Qt    = ws + 1467392;       // 25600
  float* VEC   = ws + 1492992;       // 25600
  float* ep    = ws + 1518592;       // 51200
  float* hx    = ep;                 // 2048 (aliases ep; hx dead before attn1 writes ep)

  hipMemsetAsync(hx, 0, 2048*4, stream);
  k_pre<<<868, 256, 0, stream>>>(Wih, qv, bih, ta, emb, gib, E);
  k_keys<<<dim3(64,4), 256, 0, stream>>>(qw, Wk, part);
  k_keys_red<<<256, 256, 0, stream>>>(part, bk, keysT);
  k_gemm_s2<1024,16><<<768, 256, 0, stream>>>(Wih + 1024, 2048, E, 1024, gib, gi, 3072, 25, 0);
  k_gru4<<<256, 256, 0, stream>>>(Whh, bhh, gi, dv, HC, hx);
  k_gemm_s2<1024,16><<<256, 256, 0, stream>>>(Wq, 1024, HC, 2048, bq, Qt, 1024, 25, 0);
  k_attn1<<<dim3(25,8), 256, 0, stream>>>(keysT, Qt, av, ep);
  k_attn2<<<25, 256, 0, stream>>>(ep, qw, HC);
  k_gemm_s2<2048,8><<<256, 256, 0, stream>>>(cW, 2048, HC, 2048, cb, VEC, 1024, 25, 1);
  k_gemm_big7<<<197, 1024, 0, stream>>>(oW, VEC, ob, out + 25);
  k_lstat<<<dim3(25,8), 256, 0, stream>>>(out + 25, pm, ps, pa);
  k_lfin<<<1, 64, 0, stream>>>(pm, ps, pa, Lg, out);
  k_lsub<<<dim3(197,25), 256, 0, stream>>>(out + 25, Lg);
}